// Round 6
// baseline (3395.996 us; speedup 1.0000x reference)
//
#include <hip/hip_runtime.h>
#include <hip/hip_bf16.h>
#include <cstdint>
#include <cstddef>

// Problem dims
constexpr int Bz = 128, Tz = 25, Ez = 512, Hz = 1024, Vz = 10000, Fz = 2048;

typedef unsigned short u16;
typedef __attribute__((ext_vector_type(8))) short bf16x8;   // 8 bf16 (4 VGPRs)
typedef __attribute__((ext_vector_type(4))) float f32x4;    // 4 f32 acc

__device__ __forceinline__ float sigm(float x) { return 1.f / (1.f + __expf(-x)); }
__device__ __forceinline__ float tanh_f(float x) {
    float e = __expf(-2.f * x);
    return 2.f / (1.f + e) - 1.f;
}
__device__ __forceinline__ float bf2f(u16 u) {
    return __builtin_bit_cast(float, ((unsigned)u) << 16);
}
__device__ __forceinline__ u16 f2bf(float x) {   // RNE
    unsigned u = __builtin_bit_cast(unsigned, x);
    u += 0x7fffu + ((u >> 16) & 1u);
    return (u16)(u >> 16);
}
__device__ __forceinline__ void splitbf(float x, u16& h, u16& l) {
    h = f2bf(x);
    l = f2bf(x - bf2f(h));
}

// ---------------- dtype detector (bf16=1 / f32=0) ----------------
__global__ __launch_bounds__(256) void detect_k(const u16* __restrict__ raw,
                                                int* __restrict__ flag) {
    __shared__ int sbuf[256];
    int tid = threadIdx.x, cnt = 0;
    for (int i = tid; i < 1024; i += 256) {
        u16 u = raw[2 * i];
        int e = (u >> 7) & 0xff;
        if (e >= 110 && e <= 127) cnt++;
    }
    sbuf[tid] = cnt;
    __syncthreads();
    for (int s = 128; s > 0; s >>= 1) {
        if (tid < s) sbuf[tid] += sbuf[tid + s];
        __syncthreads();
    }
    if (tid == 0) flag[0] = (sbuf[0] >= 512) ? 1 : 0;
}

__device__ __forceinline__ float ldf(const void* p, size_t i, int isbf) {
    return isbf ? bf2f(((const u16*)p)[i]) : ((const float*)p)[i];
}

// ---------------- generic value split: in -> hi/lo bf16 ----------------
__global__ __launch_bounds__(256) void vsplit_k(const void* __restrict__ in,
                                                u16* __restrict__ oh,
                                                u16* __restrict__ ol, int n,
                                                const int* __restrict__ flag) {
    int idx = blockIdx.x * 256 + threadIdx.x;
    int i4 = idx << 2;
    if (i4 >= n) return;
    int isbf = *flag;
    ushort4 h4, l4;
    float v0 = ldf(in, i4 + 0, isbf);
    float v1 = ldf(in, i4 + 1, isbf);
    float v2 = ldf(in, i4 + 2, isbf);
    float v3 = ldf(in, i4 + 3, isbf);
    splitbf(v0, h4.x, l4.x);
    splitbf(v1, h4.y, l4.y);
    splitbf(v2, h4.z, l4.z);
    splitbf(v3, h4.w, l4.w);
    *(ushort4*)&oh[i4] = h4;
    *(ushort4*)&ol[i4] = l4;
}

// ---------------- bias pack to f32 ----------------
__global__ __launch_bounds__(256) void pack2_k(
    const void* __restrict__ bp,
    const void* __restrict__ bf0, const void* __restrict__ bi0,
    const void* __restrict__ bo0, const void* __restrict__ bg0,
    const void* __restrict__ bf1, const void* __restrict__ bi1,
    const void* __restrict__ bo1, const void* __restrict__ bg1,
    const void* __restrict__ bout,
    float* __restrict__ bp_f, float* __restrict__ b0_f, float* __restrict__ b1_f,
    float* __restrict__ bout_f, const int* __restrict__ flag) {
    int idx = blockIdx.x * 256 + threadIdx.x;
    int isbf = *flag;
    if (idx < 1024) {
        bp_f[idx] = ldf(bp, idx, isbf);
    } else if (idx < 5120) {
        int n = idx - 1024, g = n >> 10, j = n & 1023;
        const void* s = (g == 0) ? bf0 : (g == 1) ? bi0 : (g == 2) ? bo0 : bg0;
        b0_f[n] = ldf(s, j, isbf);
    } else if (idx < 9216) {
        int n = idx - 5120, g = n >> 10, j = n & 1023;
        const void* s = (g == 0) ? bf1 : (g == 1) ? bi1 : (g == 2) ? bo1 : bg1;
        b1_f[n] = ldf(s, j, isbf);
    } else if (idx < 9216 + Vz) {
        int n = idx - 9216;
        bout_f[n] = ldf(bout, n, isbf);
    }
}

// ---------------- embedding gather + hi/lo split -> X0h/X0l [3200][512] --------
__global__ __launch_bounds__(256) void gsplit_k(const int* __restrict__ tok,
                                                const void* __restrict__ emb,
                                                u16* __restrict__ Xh,
                                                u16* __restrict__ Xl,
                                                const int* __restrict__ flag) {
    int idx = blockIdx.x * 256 + threadIdx.x;   // 3200*128
    if (idx >= 3200 * (Ez / 4)) return;
    int r = idx >> 7, c4 = (idx & 127) << 2;
    int t = r >> 7, b = r & 127;
    int tk = tok[b * Tz + t];
    int isbf = *flag;
    ushort4 h4, l4;
    float v0 = ldf(emb, (size_t)tk * Ez + c4 + 0, isbf);
    float v1 = ldf(emb, (size_t)tk * Ez + c4 + 1, isbf);
    float v2 = ldf(emb, (size_t)tk * Ez + c4 + 2, isbf);
    float v3 = ldf(emb, (size_t)tk * Ez + c4 + 3, isbf);
    splitbf(v0, h4.x, l4.x);
    splitbf(v1, h4.y, l4.y);
    splitbf(v2, h4.z, l4.z);
    splitbf(v3, h4.w, l4.w);
    *(ushort4*)&Xh[(size_t)r * Ez + c4] = h4;
    *(ushort4*)&Xl[(size_t)r * Ez + c4] = l4;
}

// ---------------- weight transpose + hi/lo split ------------------------------
// src W[K][Nsrc] -> Wh/Wl[(z*Nsrc + n)][K]. 64k x 32n tiles -> 128B-contig writes.
// Grid (ceil(Npad/32), K/64, nmats).
__global__ __launch_bounds__(256) void wsplit_k(
    const void* __restrict__ s0, const void* __restrict__ s1,
    const void* __restrict__ s2, const void* __restrict__ s3,
    int K, int Nsrc, u16* __restrict__ Wh, u16* __restrict__ Wl,
    const int* __restrict__ flag) {
    int z = blockIdx.z;
    const void* src = (z == 0) ? s0 : (z == 1) ? s1 : (z == 2) ? s2 : s3;
    __shared__ float tb[64][33];
    int n0 = blockIdx.x * 32, k0 = blockIdx.y * 64, tid = threadIdx.x;
    int isbf = *flag;
    for (int i = 0; i < 8; i++) {
        int idx = i * 256 + tid, k = idx >> 5, n = idx & 31;
        tb[k][n] = (n0 + n < Nsrc) ? ldf(src, (size_t)(k0 + k) * Nsrc + n0 + n, isbf)
                                   : 0.f;
    }
    __syncthreads();
    size_t dbase = (size_t)z * Nsrc;
    for (int i = 0; i < 8; i++) {
        int idx = i * 256 + tid, n = idx >> 6, k = idx & 63;
        u16 hh, ll;
        splitbf(tb[k][n], hh, ll);
        size_t o = (dbase + n0 + n) * (size_t)K + k0 + k;
        Wh[o] = hh;
        Wl[o] = ll;
    }
}

// ---------------- LSTM cell elementwise, fused 8-way partial-sum, x4 vec -------
__global__ __launch_bounds__(256) void cellu_k(
    const float* __restrict__ parts,
    const float* __restrict__ add, int astride, int amask,
    float* __restrict__ c,
    u16* __restrict__ hi1, u16* __restrict__ lo1, int ld1,
    u16* __restrict__ hi2, u16* __restrict__ lo2, int ld2) {
    int idx = blockIdx.x * 256 + threadIdx.x;   // 32768 threads, 4 elems each
    int m = idx >> 8, j4 = (idx & 255) << 2;
    size_t ab = (size_t)(m & amask) * astride + j4;
    f32x4 gf = *(const f32x4*)&add[ab];
    f32x4 gi = *(const f32x4*)&add[ab + 1024];
    f32x4 go = *(const f32x4*)&add[ab + 2048];
    f32x4 gg = *(const f32x4*)&add[ab + 3072];
    size_t base = (size_t)m * 4096 + j4;
#pragma unroll
    for (int p = 0; p < 8; ++p) {
        const float* pp = parts + (size_t)p * 524288 + base;
        gf += *(const f32x4*)&pp[0];
        gi += *(const f32x4*)&pp[1024];
        go += *(const f32x4*)&pp[2048];
        gg += *(const f32x4*)&pp[3072];
    }
    int cidx = m * 1024 + j4;
    f32x4 cv = *(const f32x4*)&c[cidx];
    ushort4 hh4, hl4;
    float hv[4];
#pragma unroll
    for (int e = 0; e < 4; ++e) {
        float f = sigm(gf[e]), ii = sigm(gi[e]), o = sigm(go[e]), g = tanh_f(gg[e]);
        float cn = f * cv[e] + ii * g;
        cv[e] = cn;
        hv[e] = o * tanh_f(cn);
    }
    *(f32x4*)&c[cidx] = cv;
    splitbf(hv[0], hh4.x, hl4.x);
    splitbf(hv[1], hh4.y, hl4.y);
    splitbf(hv[2], hh4.z, hl4.z);
    splitbf(hv[3], hh4.w, hl4.w);
    size_t o1 = (size_t)m * ld1 + j4, o2 = (size_t)m * ld2 + j4;
    *(ushort4*)&hi1[o1] = hh4;
    *(ushort4*)&lo1[o1] = hl4;
    *(ushort4*)&hi2[o2] = hh4;
    *(ushort4*)&lo2[o2] = hl4;
}

// ---------------- partial-sum reducer (+addv, leaky, optional split), x4 vec ----
template <int ACT, int SPLIT>
__global__ __launch_bounds__(256) void sumPu_k(
    const float* __restrict__ parts, int Ns,
    const float* __restrict__ addv, int astride, int amask,
    float* __restrict__ out, u16* __restrict__ ohi, u16* __restrict__ olo,
    int total) {
    int idx = blockIdx.x * 256 + threadIdx.x;
    int i4 = idx << 2;
    if (i4 >= total) return;
    int m = i4 >> Ns, col = i4 & ((1 << Ns) - 1);
    f32x4 v = *(const f32x4*)&addv[(size_t)(m & amask) * astride + col];
#pragma unroll
    for (int p = 0; p < 8; ++p)
        v += *(const f32x4*)&parts[(size_t)p * total + i4];
    if (ACT == 1) {
#pragma unroll
        for (int e = 0; e < 4; ++e) v[e] = (v[e] > 0.f) ? v[e] : 0.01f * v[e];
    }
    *(f32x4*)&out[i4] = v;
    if (SPLIT) {
        ushort4 h4, l4;
        splitbf(v[0], h4.x, l4.x);
        splitbf(v[1], h4.y, l4.y);
        splitbf(v[2], h4.z, l4.z);
        splitbf(v[3], h4.w, l4.w);
        *(ushort4*)&ohi[i4] = h4;
        *(ushort4*)&olo[i4] = l4;
    }
}

// =============================================================================
// Recurrent MFMA GEMM (bf16x3 hi/lo) -> parts[z][128][N].
// A = concat( X (XK cols from Xh/Xl) , H (Ah/Al) ), M=128. Tile 128 x 64,
// BK=64, split-K z = gridDim.x / nbn. W layout Wh/Wl[n][Kw], col = kg (+hoff
// for k>=XK; XK=0 -> always +hoff).
// =============================================================================
template <int XK>
__global__ __launch_bounds__(256, 2) void rgemm_k(
    const u16* __restrict__ Xh, const u16* __restrict__ Xl, int ldx,
    const u16* __restrict__ Ah, const u16* __restrict__ Al, int ldah,
    const u16* __restrict__ Wh, const u16* __restrict__ Wl, int ldk, int hoff,
    float* __restrict__ parts, int N, int nbn, int KC) {
    __shared__ u16 sh[27648];        // A hi/lo [128][72], B hi/lo [64][72]
    u16* sAh = sh;                   // 9216
    u16* sAl = sh + 9216;
    u16* sBh = sh + 18432;           // 4608
    u16* sBl = sh + 23040;
    const int tid = threadIdx.x;
    const int bid = blockIdx.x;
    const int bn0 = (bid % nbn) * 64;
    const int z = bid / nbn;
    const int kbase = z * KC;
    const int wid = tid >> 6, lane = tid & 63;
    const int l15 = lane & 15, g = lane >> 4;
    const int wr0 = (wid >> 1) * 64, wc0 = (wid & 1) * 32;

    f32x4 acc[4][2];
#pragma unroll
    for (int mi = 0; mi < 4; ++mi)
#pragma unroll
        for (int nj = 0; nj < 2; ++nj) acc[mi][nj] = (f32x4){0.f, 0.f, 0.f, 0.f};

    int4 pAh[4], pAl[4], pBh[2], pBl[2];
    auto stageLoad = [&](int kt) {
#pragma unroll
        for (int it = 0; it < 4; ++it) {
            int idx = it * 256 + tid;
            int row = idx >> 3, kc = (idx & 7) << 3;
            int kg = kbase + kt + kc;
            if (XK > 0 && kg < XK) {
                size_t off = (size_t)row * ldx + kg;
                pAh[it] = *(const int4*)&Xh[off];
                pAl[it] = *(const int4*)&Xl[off];
            } else {
                size_t off = (size_t)row * ldah + (kg - XK);
                pAh[it] = *(const int4*)&Ah[off];
                pAl[it] = *(const int4*)&Al[off];
            }
        }
#pragma unroll
        for (int it = 0; it < 2; ++it) {
            int idx = it * 256 + tid;
            int n = idx >> 3, kc = (idx & 7) << 3;
            int kg = kbase + kt + kc;
            int colB = kg + ((XK > 0 && kg < XK) ? 0 : hoff);
            size_t wrow = (size_t)(bn0 + n) * ldk + colB;
            pBh[it] = *(const int4*)&Wh[wrow];
            pBl[it] = *(const int4*)&Wl[wrow];
        }
    };
    auto stageWrite = [&]() {
#pragma unroll
        for (int it = 0; it < 4; ++it) {
            int idx = it * 256 + tid;
            int row = idx >> 3, kc = (idx & 7) << 3;
            *(int4*)&sAh[row * 72 + kc] = pAh[it];
            *(int4*)&sAl[row * 72 + kc] = pAl[it];
        }
#pragma unroll
        for (int it = 0; it < 2; ++it) {
            int idx = it * 256 + tid;
            int n = idx >> 3, kc = (idx & 7) << 3;
            *(int4*)&sBh[n * 72 + kc] = pBh[it];
            *(int4*)&sBl[n * 72 + kc] = pBl[it];
        }
    };

    stageLoad(0);
    for (int kt = 0; kt < KC; kt += 64) {
        stageWrite();
        __syncthreads();
        if (kt + 64 < KC) stageLoad(kt + 64);
#pragma unroll
        for (int kh = 0; kh < 2; ++kh) {
            bf16x8 bh[2], bl[2];
#pragma unroll
            for (int nj = 0; nj < 2; ++nj) {
                int co = (wc0 + nj * 16 + l15) * 72 + 32 * kh + 8 * g;
                bh[nj] = *(const bf16x8*)&sBh[co];
                bl[nj] = *(const bf16x8*)&sBl[co];
            }
#pragma unroll
            for (int mi = 0; mi < 4; ++mi) {
                int ar = (wr0 + mi * 16 + l15) * 72 + 32 * kh + 8 * g;
                bf16x8 ah = *(const bf16x8*)&sAh[ar];
                bf16x8 al = *(const bf16x8*)&sAl[ar];
#pragma unroll
                for (int nj = 0; nj < 2; ++nj) {
                    acc[mi][nj] = __builtin_amdgcn_mfma_f32_16x16x32_bf16(
                        ah, bh[nj], acc[mi][nj], 0, 0, 0);
                    acc[mi][nj] = __builtin_amdgcn_mfma_f32_16x16x32_bf16(
                        al, bh[nj], acc[mi][nj], 0, 0, 0);
                    acc[mi][nj] = __builtin_amdgcn_mfma_f32_16x16x32_bf16(
                        ah, bl[nj], acc[mi][nj], 0, 0, 0);
                }
            }
        }
        __syncthreads();
    }
    float* outp = parts + (size_t)z * 128 * N;
#pragma unroll
    for (int mi = 0; mi < 4; ++mi)
#pragma unroll
        for (int nj = 0; nj < 2; ++nj) {
            int col = bn0 + wc0 + nj * 16 + l15;
            int rowb = wr0 + mi * 16 + 4 * g;
#pragma unroll
            for (int r = 0; r < 4; ++r)
                outp[(size_t)(rowb + r) * N + col] = acc[mi][nj][r];
        }
}

// =============================================================================
// Logits MFMA GEMM (bf16x3): out[b][t][v] = hs[3200,1024] @ WoutT + bout.
// 1D grid 1000, XCD col-major chunk swizzle. 128row x 256col macro-tile.
// LDS-staged coalesced epilogue (full-line stores).
// =============================================================================
__global__ __launch_bounds__(256, 2) void lgemm_k(
    const u16* __restrict__ hs_hi, const u16* __restrict__ hs_lo,
    const u16* __restrict__ Wh, const u16* __restrict__ Wl,
    const float* __restrict__ bout_f, float* __restrict__ out) {
    __shared__ u16 sh[30720];   // staging 26112 u16; epilogue reuses as float
    u16* sAh = sh;              // [128][40]
    u16* sAl = sh + 5120;
    u16* sBh = sh + 10240;      // [256][40]
    u16* sBl = sh + 20480;
    float* fsh = (float*)sh;    // epilogue: FIDX layout, 8447 floats (33.8 KB)
    const int tid = threadIdx.x;
    // XCD swizzle: 1000 blocks, 8 chunks of 125; col-major (bx outer).
    int wg = (blockIdx.x & 7) * 125 + (blockIdx.x >> 3);
    const int bn0 = (wg / 25) * 256, bm0 = (wg % 25) * 128;
    const int wid = tid >> 6, lane = tid & 63;
    const int l15 = lane & 15, g = lane >> 4;
    const int wr0 = (wid >> 1) * 64, wc0 = (wid & 1) * 128;

    f32x4 acc[4][8];
#pragma unroll
    for (int mi = 0; mi < 4; ++mi)
#pragma unroll
        for (int nj = 0; nj < 8; ++nj) acc[mi][nj] = (f32x4){0.f, 0.f, 0.f, 0.f};

    int4 pAh[2], pAl[2], pBh[4], pBl[4];
    auto stageLoad = [&](int kt) {
#pragma unroll
        for (int it = 0; it < 2; ++it) {
            int idx = it * 256 + tid;
            int row = idx >> 2, kc = (idx & 3) << 3;
            size_t off = (size_t)(bm0 + row) * Hz + kt + kc;
            pAh[it] = *(const int4*)&hs_hi[off];
            pAl[it] = *(const int4*)&hs_lo[off];
        }
#pragma unroll
        for (int it = 0; it < 4; ++it) {
            int idx = it * 256 + tid;
            int n = idx >> 2, kc = (idx & 3) << 3;
            size_t wr = (size_t)(bn0 + n) * Hz + kt + kc;
            pBh[it] = *(const int4*)&Wh[wr];
            pBl[it] = *(const int4*)&Wl[wr];
        }
    };
    auto stageWrite = [&]() {
#pragma unroll
        for (int it = 0; it < 2; ++it) {
            int idx = it * 256 + tid;
            int row = idx >> 2, kc = (idx & 3) << 3;
            *(int4*)&sAh[row * 40 + kc] = pAh[it];
            *(int4*)&sAl[row * 40 + kc] = pAl[it];
        }
#pragma unroll
        for (int it = 0; it < 4; ++it) {
            int idx = it * 256 + tid;
            int n = idx >> 2, kc = (idx & 3) << 3;
            *(int4*)&sBh[n * 40 + kc] = pBh[it];
            *(int4*)&sBl[n * 40 + kc] = pBl[it];
        }
    };

    stageLoad(0);
    for (int kt = 0; kt < Hz; kt += 32) {
        stageWrite();
        __syncthreads();
        if (kt + 32 < Hz) stageLoad(kt + 32);
        bf16x8 ahv[4], alv[4];
#pragma unroll
        for (int mi = 0; mi < 4; ++mi) {
            int ar = (wr0 + mi * 16 + l15) * 40 + 8 * g;
            ahv[mi] = *(const bf16x8*)&sAh[ar];
            alv[mi] = *(const bf16x8*)&sAl[ar];
        }
#pragma unroll
        for (int half = 0; half < 2; ++half) {
            bf16x8 bh[4], bl[4];
#pragma unroll
            for (int n2 = 0; n2 < 4; ++n2) {
                int co = (wc0 + (half * 4 + n2) * 16 + l15) * 40 + 8 * g;
                bh[n2] = *(const bf16x8*)&sBh[co];
                bl[n2] = *(const bf16x8*)&sBl[co];
            }
#pragma unroll
            for (int mi = 0; mi < 4; ++mi) {
#pragma unroll
                for (int n2 = 0; n2 < 4; ++n2) {
                    int j = half * 4 + n2;
                    acc[mi][j] = __builtin_amdgcn_mfma_f32_16x16x32_bf16(
                        ahv[mi], bh[n2], acc[mi][j], 0, 0, 0);
                    acc[mi][j] = __builtin_amdgcn_mfma_f32_16x16x32_bf16(
                        alv[mi], bh[n2], acc[mi][j], 0, 0, 0);
                    acc[mi][j] = __builtin_amdgcn_mfma_f32_16x16x32_bf16(
                        ahv[mi], bl[n2], acc[mi][j], 0, 0, 0);
                }
            }
        }
        __syncthreads();
    }

    // -------- LDS-staged coalesced epilogue: 4 phases of 32 rows --------
    // Row footprint = 8 chunks * 33 = 264 floats (BUGFIX: was 258 -> rows
    // overlapped for cols 251..255, racing across waves).
#define FIDX(lr, col) ((lr)*264 + ((col) >> 5) * 33 + ((col)&31))
#pragma unroll 1
    for (int p = 0; p < 4; ++p) {
        __syncthreads();
#pragma unroll
        for (int mi = 0; mi < 4; ++mi) {
            int gr = wr0 + mi * 16;
            if (gr >= p * 32 && gr < p * 32 + 32) {
                int lr0 = gr - p * 32 + 4 * g;
#pragma unroll
                for (int nj = 0; nj < 8; ++nj) {
                    int col = wc0 + nj * 16 + l15;
#pragma unroll
                    for (int r = 0; r < 4; ++r)
                        fsh[FIDX(lr0 + r, col)] = acc[mi][nj][r];
                }
            }
        }
        __syncthreads();
#pragma unroll
        for (int sub = 0; sub < 2; ++sub) {
            int lr = sub * 16 + (tid >> 4);
            int cb = (tid & 15) * 4;
            int grow = bm0 + p * 32 + lr;
            int tt = grow >> 7, bb = grow & 127;
            size_t obase = ((size_t)(bb * Tz + tt)) * Vz;
#pragma unroll
            for (int j = 0; j < 4; ++j) {
                int col = cb + 64 * j;
                int gcol = bn0 + col;
                if (gcol < Vz) {
                    float4 v;
                    v.x = fsh[FIDX(lr, col + 0)] + bout_f[gcol + 0];
                    v.y = fsh[FIDX(lr, col + 1)] + bout_f[gcol + 1];
                    v.z = fsh[FIDX(lr, col + 2)] + bout_f[gcol + 2];
                    v.w = fsh[FIDX(lr, col + 3)] + bout_f[gcol + 3];
                    *(float4*)&out[obase + gcol] = v;
                }
            }
        }
    }
#undef FIDX
}

extern "C" void kernel_launch(void* const* d_in, const int* in_sizes, int n_in,
                              void* d_out, int out_size, void* d_ws, size_t ws_size,
                              hipStream_t stream) {
    const int* tokens = (const int*)d_in[0];
    const void* features = d_in[1];    // [128,2048]
    const void* embedding = d_in[2];   // [10000,512]
    const void* Wp = d_in[3];          // [2048,1024]
    const void* bp = d_in[4];
    const void* W0[4] = {d_in[5], d_in[7], d_in[9], d_in[11]};   // each [2560,1024]
    const void* b0[4] = {d_in[6], d_in[8], d_in[10], d_in[12]};
    const void* W1[4] = {d_in[13], d_in[15], d_in[17], d_in[19]}; // each [2048,1024]
    const void* b1[4] = {d_in[14], d_in[16], d_in[18], d_in[20]};
    const void* Wout = d_in[21];       // [1024,10000]
    const void* bout = d_in[22];

    char* w = (char*)d_ws;
    size_t cur = 0;
    auto alloc = [&](size_t bytes) {
        size_t o = cur;
        cur += (bytes + 255) & ~(size_t)255;
        return o;
    };
    u16* W0h = (u16*)(w + alloc((size_t)4096 * 2560 * 2));   // 20.97 MB
    u16* W0l = (u16*)(w + alloc((size_t)4096 * 2560 * 2));   // 20.97 MB
    u16* W1h = (u16*)(w + alloc((size_t)4096 * 2048 * 2));   // 16.78 MB
    u16* W1l = (u16*)(w + alloc((size_t)4096 * 2048 * 2));   // 16.78 MB
    u16* X0h = (u16*)(w + alloc((size_t)3200 * Ez * 2));     // 3.28 MB
    u16* X0l = (u16*)(w + alloc((size_t)3200 * Ez * 2));     // 3.28 MB
    u16* hs_hi = (u16*)(w + alloc((size_t)3200 * Hz * 2));   // 6.55 MB
    u16* hs_lo = (u16*)(w + alloc((size_t)3200 * Hz * 2));   // 6.55 MB
    float* parts = (float*)(w + alloc((size_t)8 * 524288 * 4)); // 16.78 MB
    float* Sfeat = (float*)(w + alloc((size_t)Bz * 4096 * 4));  // 2.10 MB
    float* featf = (float*)(w + alloc((size_t)Bz * Hz * 4));
    u16* feat_hi = (u16*)(w + alloc((size_t)Bz * Hz * 2));
    u16* feat_lo = (u16*)(w + alloc((size_t)Bz * Hz * 2));
    // zeroed state block (contiguous)
    u16* h0_hi = (u16*)(w + alloc((size_t)Bz * Hz * 2));
    u16* h0_lo = (u16*)(w + alloc((size_t)Bz * Hz * 2));
    u16* comb1_hi = (u16*)(w + alloc((size_t)Bz * 2048 * 2));
    u16* comb1_lo = (u16*)(w + alloc((size_t)Bz * 2048 * 2));
    float* c0 = (float*)(w + alloc((size_t)Bz * Hz * 4));
    float* c1 = (float*)(w + alloc((size_t)Bz * Hz * 4));
    size_t stateBytes = (size_t)Bz * Hz * 2 * 2 + (size_t)Bz * 2048 * 2 * 2 +
                        (size_t)Bz * Hz * 4 * 2;
    float* bp_f = (float*)(w + alloc(1024 * 4));
    float* b0_f = (float*)(w + alloc(4096 * 4));
    float* b1_f = (float*)(w + alloc(4096 * 4));
    float* bout_f = (float*)(w + alloc((size_t)Vz * 4));
    int* dflag = (int*)(w + alloc(256));
    (void)ws_size; (void)in_sizes; (void)n_in; (void)out_size;

    // Aliases (mutually exclusive lifetimes):
    // Wout split (10240x1024 x2 = 20.97 MB each) over W0h/W0l, built after loop.
    u16* Wouth = W0h;
    u16* Woutl = W0l;
    // Wp split (1024x2048 x2 = 4.19 MB each) over hs_hi/hs_lo (hs written in loop).
    u16* Wpth = hs_hi;
    u16* Wptl = hs_lo;
    // features split (128x2048 x2 = 0.5 MB each) over Sfeat (written later).
    u16* fc_hi = (u16*)Sfeat;
    u16* fc_lo = fc_hi + (size_t)Bz * Fz;

    // 0) dtype detect
    detect_k<<<1, 256, 0, stream>>>((const u16*)embedding, dflag);

    // 1) zero states
    hipMemsetAsync(h0_hi, 0, stateBytes, stream);

    // 2) biases, feature/embedding splits, weight transpose+splits
    pack2_k<<<76, 256, 0, stream>>>(bp, b0[0], b0[1], b0[2], b0[3],
                                    b1[0], b1[1], b1[2], b1[3], bout,
                                    bp_f, b0_f, b1_f, bout_f, dflag);
    vsplit_k<<<256, 256, 0, stream>>>(features, fc_hi, fc_lo, Bz * Fz, dflag);
    gsplit_k<<<1600, 256, 0, stream>>>(tokens, embedding, X0h, X0l, dflag);
    wsplit_k<<<dim3(32, 40, 4), 256, 0, stream>>>(
        W0[0], W0[1], W0[2], W0[3], 2560, 1024, W0h, W0l, dflag);
    wsplit_k<<<dim3(32, 32, 4), 256, 0, stream>>>(
        W1[0], W1[1], W1[2], W1[3], 2048, 1024, W1h, W1l, dflag);
    wsplit_k<<<dim3(32, 32, 1), 256, 0, stream>>>(
        Wp, Wp, Wp, Wp, 2048, 1024, Wpth, Wptl, dflag);

    // 3) feat = leaky_relu(features @ Wp + bp)  (MFMA, N=1024, z=8, KC=256)
    rgemm_k<0><<<128, 256, 0, stream>>>(
        nullptr, nullptr, 0, fc_hi, fc_lo, 2048,
        Wpth, Wptl, 2048, 0, parts, 1024, 16, 256);
    sumPu_k<1, 1><<<128, 256, 0, stream>>>(parts, 10, bp_f, 0, 0,
                                           featf, feat_hi, feat_lo, Bz * Hz);

    // 4) Sfeat = feat @ W0[rows 512:1536] + b0   (MFMA, N=4096, z=8, KC=128)
    rgemm_k<0><<<512, 256, 0, stream>>>(
        nullptr, nullptr, 0, feat_hi, feat_lo, 1024,
        W0h, W0l, 2560, 512, parts, 4096, 64, 128);
    sumPu_k<0, 0><<<512, 256, 0, stream>>>(parts, 12, b0_f, 0, 0,
                                           Sfeat, nullptr, nullptr, Bz * 4096);

    // 5) time loop (MFMA split-K z=8, BK=64)
    for (int t = 0; t < Tz; t++) {
        // layer 0: [x_t | h0] @ W0[[0:512)+(1536:2560)]  K=1536, KC=192
        rgemm_k<512><<<512, 256, 0, stream>>>(
            X0h + (size_t)t * 128 * Ez, X0l + (size_t)t * 128 * Ez, Ez,
            h0_hi, h0_lo, 1024, W0h, W0l, 2560, 1024, parts, 4096, 64, 192);
        cellu_k<<<128, 256, 0, stream>>>(
            parts, Sfeat, 4096, 127, c0,
            h0_hi, h0_lo, 1024, comb1_hi, comb1_lo, 2048);
        // layer 1: [h0n | h1] @ W1  K=2048, KC=256
        rgemm_k<0><<<512, 256, 0, stream>>>(
            nullptr, nullptr, 0, comb1_hi, comb1_lo, 2048,
            W1h, W1l, 2048, 0, parts, 4096, 64, 256);
        cellu_k<<<128, 256, 0, stream>>>(
            parts, b1_f, 0, 0, c1,
            hs_hi + (size_t)t * 128 * Hz, hs_lo + (size_t)t * 128 * Hz, 1024,
            comb1_hi + 1024, comb1_lo + 1024, 2048);
    }

    // 6) Wout transpose+split into aliased region (after last W0 use)
    wsplit_k<<<dim3(320, 16, 1), 256, 0, stream>>>(
        Wout, Wout, Wout, Wout, 1024, Vz, Wouth, Woutl, dflag);

    // 7) logits (MFMA bf16x3, coalesced epilogue) -> out[b][t][v] f32
    lgemm_k<<<1000, 256, 0, stream>>>(hs_hi, hs_lo, Wouth, Woutl,
                                      bout_f, (float*)d_out);
}